// Round 1
// baseline (194.708 us; speedup 1.0000x reference)
//
#include <hip/hip_runtime.h>
#include <hip/hip_bf16.h>
#include <cstdint>

// Problem constants (fixed by setup_inputs)
#define B_    32
#define T_    4096
#define C_    256
#define NOUT  512   // GEMM N: 256 value + 256 gate
#define BM    64    // rows (time steps) per block
#define DMAX  16    // max supported dilation (problem uses 4)

typedef __attribute__((ext_vector_type(8))) short bf16x8;
typedef __attribute__((ext_vector_type(4))) float f32x4;
typedef __attribute__((ext_vector_type(4))) short s16x4;

static __device__ __forceinline__ short f2bf(float f) {
  union { float f; uint32_t u; } v; v.f = f;
  uint32_t u = v.u;
  return (short)((u + 0x7fffu + ((u >> 16) & 1u)) >> 16);  // RNE
}

// ---------------------------------------------------------------------------
// Prep: build bf16 weight image in ws, laid out EXACTLY as the per-k-step LDS
// tile (32 KiB per k-step of 32), XOR-swizzled: byte = (n*64 + kk*2) ^ ((n&7)<<4).
// n in [0,512): n<256 -> value feature f=n (Wv), else gate feature f=n-256 (Wg).
// k = 32*ks + kk: k<256 -> tap0 (x[t-d]), else tap1 (x[t]).
// Also bcat[512] = [bv ; bg] fp32.
// ---------------------------------------------------------------------------
__global__ void prep_weights(const float* __restrict__ Wv, const float* __restrict__ Wg,
                             const float* __restrict__ bv, const float* __restrict__ bg,
                             short* __restrict__ wimg, float* __restrict__ bcat) {
  int id = blockIdx.x * 256 + threadIdx.x;     // 16*512*32 = 262144 total
  int f   = id & 255;
  int sel = (id >> 8) & 1;
  int kk  = (id >> 9) & 31;
  int ks  = id >> 14;
  int k   = ks * 32 + kk;
  int tap = k >> 8;
  int kr  = k & 255;
  const float* W = sel ? Wg : Wv;
  float w = W[((size_t)tap * 256 + kr) * 256 + f];
  int n = sel * 256 + f;
  int byte_off = (n * 64 + kk * 2) ^ ((n & 7) << 4);
  wimg[ks * 16384 + (byte_off >> 1)] = f2bf(w);
  if (id < 512) bcat[id] = (id < 256) ? bv[id] : bg[id - 256];
}

// ---------------------------------------------------------------------------
// Main: one block = 64 time rows of one batch, full N=512.
// 4 waves split N: wave w owns value cols [64w,64w+64) AND gate cols
// [256+64w, 256+64w+64) so v/g pairs land in the same lane for the epilogue.
// ---------------------------------------------------------------------------
__global__ __launch_bounds__(256, 2) void snail_main(
    const float* __restrict__ x, const short* __restrict__ wimg,
    const float* __restrict__ bcat, const int* __restrict__ dptr,
    float* __restrict__ out) {
  __shared__ __align__(16) short lx[(BM + DMAX) * C_];  // 40 KiB, swizzled bf16 x-tile
  __shared__ __align__(16) short lw[NOUT * 32];         // 32 KiB, one k-step of weights

  const int d    = *dptr;
  const int bid  = blockIdx.x;
  const int b    = bid >> 6;        // T_/BM = 64 tiles per batch
  const int t0   = (bid & 63) * BM;
  const int tid  = threadIdx.x;
  const int lane = tid & 63;
  const int w    = tid >> 6;
  const int row15 = lane & 15;
  const int qw    = lane >> 4;      // quarter-wave 0..3

  const float* xb = x + (size_t)b * T_ * C_;

  // ---- stage X rows t0-d .. t0+BM-1 into LDS rows 0..BM+d-1 (bf16, swizzled)
  const int nrows = BM + d;
  for (int i = tid; i < nrows * 64; i += 256) {
    int r = i >> 6, c4 = i & 63;
    int t = t0 - d + r;
    float4 v = make_float4(0.f, 0.f, 0.f, 0.f);
    if (t >= 0) v = *(const float4*)(xb + (size_t)t * C_ + c4 * 4);
    s16x4 s;
    s.x = f2bf(v.x); s.y = f2bf(v.y); s.z = f2bf(v.z); s.w = f2bf(v.w);
    int byte = (r * 512 + c4 * 8) ^ ((r & 7) << 4);
    *(s16x4*)((char*)lx + byte) = s;
  }

  f32x4 accv[4][4], accg[4][4];
#pragma unroll
  for (int mi = 0; mi < 4; ++mi)
#pragma unroll
    for (int ni = 0; ni < 4; ++ni) {
      accv[mi][ni] = (f32x4){0.f, 0.f, 0.f, 0.f};
      accg[mi][ni] = (f32x4){0.f, 0.f, 0.f, 0.f};
    }

  typedef const __attribute__((address_space(1))) unsigned int* gp_t;
  typedef __attribute__((address_space(3))) unsigned int* lp_t;

  for (int ks = 0; ks < 16; ++ks) {
    __syncthreads();   // prior-iteration lw reads done (also covers lx writes at ks=0)
    {
      const char* src = (const char*)wimg + ks * 32768;
      char* dstw = (char*)lw + w * 1024;            // wave-uniform LDS base
      const char* gsrc = src + tid * 16;            // per-lane global source
#pragma unroll
      for (int c = 0; c < 8; ++c)
        __builtin_amdgcn_global_load_lds((gp_t)(const void*)(gsrc + c * 4096),
                                         (lp_t)(void*)(dstw + c * 4096), 16, 0, 0);
    }
    __syncthreads();   // compiler drains vmcnt(0) before barrier -> lw ready

    // A fragments: lane holds A[row=lane&15][k=qw*8+j]
    bf16x8 af[4];
    const int rofs = (ks >= 8) ? d : 0;
    const int cb = (ks & 7) * 64 + qw * 16;
#pragma unroll
    for (int mi = 0; mi < 4; ++mi) {
      int r = 16 * mi + row15 + rofs;
      int byte = (r * 512 + cb) ^ ((r & 7) << 4);
      af[mi] = *(const bf16x8*)((const char*)lx + byte);
    }
#pragma unroll
    for (int ni = 0; ni < 4; ++ni) {
      int nv = w * 64 + 16 * ni + row15;
      bf16x8 bv_ = *(const bf16x8*)((const char*)lw +
                    ((nv * 64 + qw * 16) ^ ((nv & 7) << 4)));
      int ng = 256 + nv;
      bf16x8 bg_ = *(const bf16x8*)((const char*)lw +
                    ((ng * 64 + qw * 16) ^ ((ng & 7) << 4)));
#pragma unroll
      for (int mi = 0; mi < 4; ++mi) {
        accv[mi][ni] = __builtin_amdgcn_mfma_f32_16x16x32_bf16(af[mi], bv_, accv[mi][ni], 0, 0, 0);
        accg[mi][ni] = __builtin_amdgcn_mfma_f32_16x16x32_bf16(af[mi], bg_, accg[mi][ni], 0, 0, 0);
      }
    }
  }

  // ---- epilogue: activations = tanh(v+bv) * sigmoid(g+bg)
  float* ob = out + (size_t)b * T_ * NOUT;
#pragma unroll
  for (int ni = 0; ni < 4; ++ni) {
    int f = w * 64 + 16 * ni + row15;
    float biasv = bcat[f], biasg = bcat[256 + f];
#pragma unroll
    for (int mi = 0; mi < 4; ++mi) {
      int rbase = t0 + 16 * mi + qw * 4;   // C/D: row=(lane>>4)*4+j, col=lane&15
      f32x4 v = accv[mi][ni], g = accg[mi][ni];
#pragma unroll
      for (int j = 0; j < 4; ++j) {
        float vv = v[j] + biasv, gg = g[j] + biasg;
        float th = 1.f - 2.f / (__expf(2.f * vv) + 1.f);
        float sg = 1.f / (1.f + __expf(-gg));
        ob[(size_t)(rbase + j) * NOUT + f] = th * sg;
      }
    }
  }

  // ---- exact fp32 passthrough: out[:, :, 256:512] = x (rows L2-hot)
  for (int i = tid; i < BM * 64; i += 256) {
    int r = i >> 6, c4 = i & 63;
    float4 v = *(const float4*)(xb + (size_t)(t0 + r) * C_ + c4 * 4);
    *(float4*)(ob + (size_t)(t0 + r) * NOUT + C_ + c4 * 4) = v;
  }
}

extern "C" void kernel_launch(void* const* d_in, const int* in_sizes, int n_in,
                              void* d_out, int out_size, void* d_ws, size_t ws_size,
                              hipStream_t stream) {
  const float* x  = (const float*)d_in[0];
  const float* Wv = (const float*)d_in[1];
  const float* bv = (const float*)d_in[2];
  const float* Wg = (const float*)d_in[3];
  const float* bg = (const float*)d_in[4];
  const int* dil  = (const int*)d_in[5];
  float* out = (float*)d_out;

  short* wimg = (short*)d_ws;                          // 512 KiB weight image
  float* bcat = (float*)((char*)d_ws + 16 * 32768);    // 2 KiB biases

  prep_weights<<<1024, 256, 0, stream>>>(Wv, Wg, bv, bg, wimg, bcat);
  snail_main<<<B_ * (T_ / BM), 256, 0, stream>>>(x, wimg, bcat, dil, out);
}